// Round 1
// baseline (37.052 us; speedup 1.0000x reference)
//
#include <hip/hip_runtime.h>
#include <hip/hip_bf16.h>

#define CIN 32
#define HH 64
#define WW 64
#define KK 64
#define NLEAF 8
#define PADDING 2

// The 16 soft-LUT coefficient rows (constant, 1/a/b/ab basis)
__device__ __constant__ float d_C[16][4] = {
    {0, 0, 0, 0},  {0, 0, 0, 1},  {0, 1, 0, -1}, {0, 1, 0, 0},
    {0, 0, 1, -1}, {0, 0, 1, 0},  {0, 1, 1, -2}, {0, 1, 1, -1},
    {1, -1, -1, 1},{1, -1, -1, 2},{1, 0, -1, 0}, {1, 0, -1, 1},
    {1, -1, 0, 0}, {1, -1, 0, 1}, {1, 0, 0, -1}, {1, 0, 0, 0}
};

// coef[k*60 + node*4 + c]; node: 0..7 = level0, 8..11 = level1, 12..13 = level2, 14 = root
__global__ void coef_kernel(const float* __restrict__ w0, const float* __restrict__ w1,
                            const float* __restrict__ w2, const float* __restrict__ w3,
                            float* __restrict__ coef) {
    int t = blockIdx.x * blockDim.x + threadIdx.x;
    if (t >= KK * 15) return;
    int k = t / 15, node = t % 15;
    const float* wp; int n;
    if (node < 8)       { wp = w0; n = node; }
    else if (node < 12) { wp = w1; n = node - 8; }
    else if (node < 14) { wp = w2; n = node - 12; }
    else                { wp = w3; n = 0; }
    const float* l = wp + (n * KK + k) * 16;
    float m = l[0];
    #pragma unroll
    for (int g = 1; g < 16; ++g) m = fmaxf(m, l[g]);
    float p[16], s = 0.f;
    #pragma unroll
    for (int g = 0; g < 16; ++g) { p[g] = expf(l[g] - m); s += p[g]; }
    float inv = 1.f / s;
    float c0 = 0, c1 = 0, c2 = 0, c3 = 0;
    #pragma unroll
    for (int g = 0; g < 16; ++g) {
        float w = p[g] * inv;
        c0 = fmaf(w, d_C[g][0], c0);
        c1 = fmaf(w, d_C[g][1], c1);
        c2 = fmaf(w, d_C[g][2], c2);
        c3 = fmaf(w, d_C[g][3], c3);
    }
    float* o = coef + t * 4;
    o[0] = c0; o[1] = c1; o[2] = c2; o[3] = c3;
}

// gate: c0 + c1*a + c2*b + c3*a*b = fma(b, fma(a,c3,c2), fma(a,c1,c0))
__device__ __forceinline__ float gate(const float* c, float a, float b) {
    return fmaf(b, fmaf(a, c[3], c[2]), fmaf(a, c[1], c[0]));
}

__global__ __launch_bounds__(256) void logic_conv_kernel(
    const float* __restrict__ x,
    const int* __restrict__ idx_h, const int* __restrict__ idx_w, const int* __restrict__ idx_c,
    const float* __restrict__ coef, float* __restrict__ out)
{
    __shared__ int   s_cb[16], s_dh[16], s_dw[16];
    __shared__ float s_coef[15][4];

    int tile = blockIdx.x & 3;        // 4 tiles of 1024 pixels per (b,k)
    int bk   = blockIdx.x >> 2;
    int k    = bk & (KK - 1);
    int tid  = threadIdx.x;

    if (tid < 16) {
        int s = tid >> 3, n = tid & 7;                 // [0..7]=a-leaves, [8..15]=b-leaves
        int off = s * (KK * NLEAF) + k * NLEAF + n;
        s_cb[tid] = idx_c[off] * (HH * WW);
        s_dh[tid] = idx_h[off] - PADDING;
        s_dw[tid] = idx_w[off] - PADDING;
    }
    if (tid < 60) {
        s_coef[tid >> 2][tid & 3] = coef[k * 60 + tid];
    }
    __syncthreads();

    const float* xb   = x + (size_t)(bk >> 6) * (CIN * HH * WW);  // b = bk/64
    float*       outp = out + ((size_t)bk << 12);
    int p0 = tile * 1024 + tid;

    #pragma unroll
    for (int it = 0; it < 4; ++it) {
        int p  = p0 + it * 256;
        int oh = p >> 6, ow = p & 63;
        float v[8];
        #pragma unroll
        for (int n = 0; n < 8; ++n) {
            float a = 0.f, bb = 0.f;
            {
                int ih = oh + s_dh[n], iw = ow + s_dw[n];
                if ((unsigned)ih < HH && (unsigned)iw < WW)
                    a = xb[s_cb[n] + ih * WW + iw];
            }
            {
                int ih = oh + s_dh[8 + n], iw = ow + s_dw[8 + n];
                if ((unsigned)ih < HH && (unsigned)iw < WW)
                    bb = xb[s_cb[8 + n] + ih * WW + iw];
            }
            v[n] = gate(s_coef[n], a, bb);
        }
        float u[4];
        #pragma unroll
        for (int n = 0; n < 4; ++n)
            u[n] = gate(s_coef[8 + n], v[2 * n], v[2 * n + 1]);
        float t0 = gate(s_coef[12], u[0], u[1]);
        float t1 = gate(s_coef[13], u[2], u[3]);
        outp[p] = gate(s_coef[14], t0, t1);
    }
}

extern "C" void kernel_launch(void* const* d_in, const int* in_sizes, int n_in,
                              void* d_out, int out_size, void* d_ws, size_t ws_size,
                              hipStream_t stream) {
    const float* x     = (const float*)d_in[0];
    const int*   idx_h = (const int*)d_in[1];
    const int*   idx_w = (const int*)d_in[2];
    const int*   idx_c = (const int*)d_in[3];
    const float* w0    = (const float*)d_in[4];
    const float* w1    = (const float*)d_in[5];
    const float* w2    = (const float*)d_in[6];
    const float* w3    = (const float*)d_in[7];
    float* out  = (float*)d_out;
    float* coef = (float*)d_ws;   // 64*15*4 floats = 15360 B

    hipLaunchKernelGGL(coef_kernel, dim3(4), dim3(256), 0, stream, w0, w1, w2, w3, coef);
    // 16 b * 64 k * 4 tiles = 4096 blocks, 256 threads, 4 pixels/thread
    hipLaunchKernelGGL(logic_conv_kernel, dim3(4096), dim3(256), 0, stream,
                       x, idx_h, idx_w, idx_c, coef, out);
}

// Round 2
// 34.876 us; speedup vs baseline: 1.0624x; 1.0624x over previous
//
#include <hip/hip_runtime.h>
#include <hip/hip_bf16.h>

#define CIN 32
#define HH 64
#define WW 64
#define KK 64
#define NLEAF 8
#define PADDING 2
#define PH 68
#define PW 68
#define PIMG (PH * PW)   // 4624

__device__ __constant__ float d_C[16][4] = {
    {0, 0, 0, 0},  {0, 0, 0, 1},  {0, 1, 0, -1}, {0, 1, 0, 0},
    {0, 0, 1, -1}, {0, 0, 1, 0},  {0, 1, 1, -2}, {0, 1, 1, -1},
    {1, -1, -1, 1},{1, -1, -1, 2},{1, 0, -1, 0}, {1, 0, -1, 1},
    {1, -1, 0, 0}, {1, -1, 0, 1}, {1, 0, 0, -1}, {1, 0, 0, 0}
};

// coef[k*60 + node*4 + c]; nodes 0..7 = level0, 8..11 = level1, 12..13 = level2, 14 = root
__global__ void coef_kernel(const float* __restrict__ w0, const float* __restrict__ w1,
                            const float* __restrict__ w2, const float* __restrict__ w3,
                            float* __restrict__ coef) {
    int t = blockIdx.x * blockDim.x + threadIdx.x;
    if (t >= KK * 15) return;
    int k = t / 15, node = t % 15;
    const float* wp; int n;
    if (node < 8)       { wp = w0; n = node; }
    else if (node < 12) { wp = w1; n = node - 8; }
    else if (node < 14) { wp = w2; n = node - 12; }
    else                { wp = w3; n = 0; }
    const float* l = wp + (n * KK + k) * 16;
    float m = l[0];
    #pragma unroll
    for (int g = 1; g < 16; ++g) m = fmaxf(m, l[g]);
    float p[16], s = 0.f;
    #pragma unroll
    for (int g = 0; g < 16; ++g) { p[g] = expf(l[g] - m); s += p[g]; }
    float inv = 1.f / s;
    float c0 = 0, c1 = 0, c2 = 0, c3 = 0;
    #pragma unroll
    for (int g = 0; g < 16; ++g) {
        float w = p[g] * inv;
        c0 = fmaf(w, d_C[g][0], c0);
        c1 = fmaf(w, d_C[g][1], c1);
        c2 = fmaf(w, d_C[g][2], c2);
        c3 = fmaf(w, d_C[g][3], c3);
    }
    float* o = coef + t * 4;
    o[0] = c0; o[1] = c1; o[2] = c2; o[3] = c3;
}

// Zero-padded copy: xpad[b,c,68,68], interior [2..65] = x[b,c,:,:]
__global__ __launch_bounds__(256) void pad_kernel(const float* __restrict__ x,
                                                  float* __restrict__ xpad) {
    int t = blockIdx.x * 256 + threadIdx.x;
    const int total = 16 * CIN * PIMG;   // 2,367,488 = 2312 * 1024
    #pragma unroll
    for (int it = 0; it < 4; ++it) {
        int e = t + it * (2312 * 256);
        if (e >= total) break;
        int bc = e / PIMG;
        int r  = e - bc * PIMG;
        int ph = r / PW;
        int pw = r - ph * PW;
        int ih = ph - PADDING, iw = pw - PADDING;
        float v = 0.f;
        if ((unsigned)ih < HH && (unsigned)iw < WW)
            v = x[bc * (HH * WW) + ih * WW + iw];
        xpad[e] = v;
    }
}

__device__ __forceinline__ float gate(const float* c, float a, float b) {
    return fmaf(b, fmaf(a, c[3], c[2]), fmaf(a, c[1], c[0]));
}

__global__ __launch_bounds__(256) void logic_conv_kernel(
    const float* __restrict__ xpad,
    const int* __restrict__ idx_h, const int* __restrict__ idx_w, const int* __restrict__ idx_c,
    const float* __restrict__ coef, float* __restrict__ out)
{
    int tile = blockIdx.x & 3;        // 4 tiles of 1024 pixels per (b,k)
    int bk   = blockIdx.x >> 2;
    int k    = bk & (KK - 1);
    int b    = bk >> 6;

    const float* xb = xpad + (size_t)b * (CIN * PIMG);

    // Per-leaf fused offsets -> wave-uniform, force to SGPR.
    int soff[16];
    #pragma unroll
    for (int n = 0; n < 16; ++n) {
        int s = n >> 3, leaf = n & 7;
        int o  = s * (KK * NLEAF) + k * NLEAF + leaf;
        int c  = idx_c[o];
        int dh = idx_h[o];
        int dw = idx_w[o];
        soff[n] = __builtin_amdgcn_readfirstlane(c * PIMG + dh * PW + dw);
    }
    // Coefs in registers (aligned float4 loads: k*60 floats = k*240 B, 16B-aligned)
    float cf[15][4];
    #pragma unroll
    for (int nd = 0; nd < 15; ++nd) {
        float4 c4 = ((const float4*)(coef + k * 60))[nd];
        cf[nd][0] = c4.x; cf[nd][1] = c4.y; cf[nd][2] = c4.z; cf[nd][3] = c4.w;
    }

    float* outp = out + ((size_t)bk << 12);
    int p0 = tile * 1024 + threadIdx.x;

    #pragma unroll
    for (int it = 0; it < 4; ++it) {
        int p  = p0 + it * 256;
        int rb = (p >> 6) * PW + (p & 63);   // oh*68 + ow in padded image
        float v[8];
        #pragma unroll
        for (int n = 0; n < 8; ++n) {
            float a  = xb[soff[n]     + rb];
            float bb = xb[soff[8 + n] + rb];
            v[n] = gate(cf[n], a, bb);
        }
        float u[4];
        #pragma unroll
        for (int n = 0; n < 4; ++n)
            u[n] = gate(cf[8 + n], v[2 * n], v[2 * n + 1]);
        float t0 = gate(cf[12], u[0], u[1]);
        float t1 = gate(cf[13], u[2], u[3]);
        outp[p] = gate(cf[14], t0, t1);
    }
}

extern "C" void kernel_launch(void* const* d_in, const int* in_sizes, int n_in,
                              void* d_out, int out_size, void* d_ws, size_t ws_size,
                              hipStream_t stream) {
    const float* x     = (const float*)d_in[0];
    const int*   idx_h = (const int*)d_in[1];
    const int*   idx_w = (const int*)d_in[2];
    const int*   idx_c = (const int*)d_in[3];
    const float* w0    = (const float*)d_in[4];
    const float* w1    = (const float*)d_in[5];
    const float* w2    = (const float*)d_in[6];
    const float* w3    = (const float*)d_in[7];
    float* out  = (float*)d_out;

    float* coef = (float*)d_ws;                         // 15,360 B
    float* xpad = (float*)((char*)d_ws + 16384);        // 9,467,904 B

    hipLaunchKernelGGL(coef_kernel, dim3(4), dim3(256), 0, stream, w0, w1, w2, w3, coef);
    hipLaunchKernelGGL(pad_kernel, dim3(2312), dim3(256), 0, stream, x, xpad);
    hipLaunchKernelGGL(logic_conv_kernel, dim3(4096), dim3(256), 0, stream,
                       xpad, idx_h, idx_w, idx_c, coef, out);
}

// Round 3
// 31.739 us; speedup vs baseline: 1.1674x; 1.0988x over previous
//
#include <hip/hip_runtime.h>
#include <hip/hip_bf16.h>

#define CIN 32
#define HH 64
#define WW 64
#define KK 64
#define NLEAF 8
#define PADDING 2
#define PH 68
#define PW 68
#define PIMG (PH * PW)   // 4624
#define NPADBLK 2312     // 16*32*4624 / 1024 elements, 4 per thread

__device__ __constant__ float d_C[16][4] = {
    {0, 0, 0, 0},  {0, 0, 0, 1},  {0, 1, 0, -1}, {0, 1, 0, 0},
    {0, 0, 1, -1}, {0, 0, 1, 0},  {0, 1, 1, -2}, {0, 1, 1, -1},
    {1, -1, -1, 1},{1, -1, -1, 2},{1, 0, -1, 0}, {1, 0, -1, 1},
    {1, -1, 0, 0}, {1, -1, 0, 1}, {1, 0, 0, -1}, {1, 0, 0, 0}
};

// Fused: blocks [0,2312) zero-pad x -> xpad; blocks [2312,2316) compute coefs.
__global__ __launch_bounds__(256) void prep_kernel(
    const float* __restrict__ x,
    const float* __restrict__ w0, const float* __restrict__ w1,
    const float* __restrict__ w2, const float* __restrict__ w3,
    float* __restrict__ coef, float* __restrict__ xpad)
{
    int blk = blockIdx.x;
    if (blk < NPADBLK) {
        int t = blk * 256 + threadIdx.x;
        #pragma unroll
        for (int it = 0; it < 4; ++it) {
            int e  = t + it * (NPADBLK * 256);
            int bc = e / PIMG;
            int r  = e - bc * PIMG;
            int ph = r / PW;
            int pw = r - ph * PW;
            int ih = ph - PADDING, iw = pw - PADDING;
            float v = 0.f;
            if ((unsigned)ih < HH && (unsigned)iw < WW)
                v = x[bc * (HH * WW) + ih * WW + iw];
            xpad[e] = v;
        }
        return;
    }
    int t = (blk - NPADBLK) * 256 + threadIdx.x;
    if (t >= KK * 15) return;
    int k = t / 15, node = t % 15;
    const float* wp; int n;
    if (node < 8)       { wp = w0; n = node; }
    else if (node < 12) { wp = w1; n = node - 8; }
    else if (node < 14) { wp = w2; n = node - 12; }
    else                { wp = w3; n = 0; }
    const float* l = wp + (n * KK + k) * 16;
    float m = l[0];
    #pragma unroll
    for (int g = 1; g < 16; ++g) m = fmaxf(m, l[g]);
    float p[16], s = 0.f;
    #pragma unroll
    for (int g = 0; g < 16; ++g) { p[g] = expf(l[g] - m); s += p[g]; }
    float inv = 1.f / s;
    float c0 = 0, c1 = 0, c2 = 0, c3 = 0;
    #pragma unroll
    for (int g = 0; g < 16; ++g) {
        float w = p[g] * inv;
        c0 = fmaf(w, d_C[g][0], c0);
        c1 = fmaf(w, d_C[g][1], c1);
        c2 = fmaf(w, d_C[g][2], c2);
        c3 = fmaf(w, d_C[g][3], c3);
    }
    float* o = coef + t * 4;
    o[0] = c0; o[1] = c1; o[2] = c2; o[3] = c3;
}

__device__ __forceinline__ float gate(const float* c, float a, float b) {
    return fmaf(b, fmaf(a, c[3], c[2]), fmaf(a, c[1], c[0]));
}

// One block per (b,k); 256 threads x 16 pixels.
__global__ __launch_bounds__(256) void logic_conv_kernel(
    const float* __restrict__ xpad,
    const int* __restrict__ idx_h, const int* __restrict__ idx_w, const int* __restrict__ idx_c,
    const float* __restrict__ coef, float* __restrict__ out)
{
    int bk = blockIdx.x;
    int k  = bk & (KK - 1);
    int b  = bk >> 6;

    const float* xb = xpad + (size_t)b * (CIN * PIMG);

    // Per-leaf SGPR base pointers (wave-uniform).
    const float* bp[16];
    #pragma unroll
    for (int n = 0; n < 16; ++n) {
        int s = n >> 3, leaf = n & 7;
        int o = s * (KK * NLEAF) + k * NLEAF + leaf;
        int off = __builtin_amdgcn_readfirstlane(idx_c[o] * PIMG + idx_h[o] * PW + idx_w[o]);
        bp[n] = xb + off;
    }

    float cf[15][4];
    #pragma unroll
    for (int nd = 0; nd < 15; ++nd) {
        float4 c4 = ((const float4*)(coef + k * 60))[nd];
        cf[nd][0] = c4.x; cf[nd][1] = c4.y; cf[nd][2] = c4.z; cf[nd][3] = c4.w;
    }

    float* outp = out + ((size_t)bk << 12);
    int tid = threadIdx.x;
    int rb0 = (tid >> 6) * PW + (tid & 63);   // row-base in padded image

    #pragma unroll
    for (int it = 0; it < 16; ++it) {
        int rb = rb0 + it * (4 * PW);          // +256 pixels = +4 rows
        float v[8];
        #pragma unroll
        for (int n = 0; n < 8; ++n) {
            float a  = bp[n][rb];
            float bb = bp[8 + n][rb];
            v[n] = gate(cf[n], a, bb);
        }
        float u[4];
        #pragma unroll
        for (int n = 0; n < 4; ++n)
            u[n] = gate(cf[8 + n], v[2 * n], v[2 * n + 1]);
        float t0 = gate(cf[12], u[0], u[1]);
        float t1 = gate(cf[13], u[2], u[3]);
        outp[tid + it * 256] = gate(cf[14], t0, t1);
    }
}

extern "C" void kernel_launch(void* const* d_in, const int* in_sizes, int n_in,
                              void* d_out, int out_size, void* d_ws, size_t ws_size,
                              hipStream_t stream) {
    const float* x     = (const float*)d_in[0];
    const int*   idx_h = (const int*)d_in[1];
    const int*   idx_w = (const int*)d_in[2];
    const int*   idx_c = (const int*)d_in[3];
    const float* w0    = (const float*)d_in[4];
    const float* w1    = (const float*)d_in[5];
    const float* w2    = (const float*)d_in[6];
    const float* w3    = (const float*)d_in[7];
    float* out  = (float*)d_out;

    float* coef = (float*)d_ws;                         // 15,360 B
    float* xpad = (float*)((char*)d_ws + 16384);        // 9,469,952 B

    hipLaunchKernelGGL(prep_kernel, dim3(NPADBLK + 4), dim3(256), 0, stream,
                       x, w0, w1, w2, w3, coef, xpad);
    // one block per (b,k): 16*64 = 1024 blocks
    hipLaunchKernelGGL(logic_conv_kernel, dim3(1024), dim3(256), 0, stream,
                       xpad, idx_h, idx_w, idx_c, coef, out);
}